// Round 7
// baseline (123.499 us; speedup 1.0000x reference)
//
#include <hip/hip_runtime.h>

// CensusLoss = mean |census(pred)-census(target)| = mismatch_count / (8*48*512*512).
// Fused kernel, 64x32 tile, 512 threads, RPT=4 px rows per thread (R3's proven
// non-spilling register footprint: 28 array floats, fits the 64-VGPR cap of
// __launch_bounds__(512,8); R4/R5's RPT=8 shape spilled 172B/thread to scratch
// => WRITE_SIZE 44MB, that was the whole regression).
// - Gray on the fly into column-major flat LDS, column pitch 44 + swizzle
//   base(lx) = lx*44 + 4*((lx>>2)&7): columns stay 16B-aligned (b128 reads),
//   staging writes spread over 8+ banks instead of 2.
// - Interior-x blocks stage with float4 global loads; x-edge blocks scalar.
// - Wave-split pipeline: stage rows 0..21 | waves0-3 compute px rows 0..15
//   while waves4-7 stage rows 22..37 | sync | waves4-7 compute rows 16..31.

#define BATCH 8
#define HH 512
#define WW 512
#define PLANE (HH * WW)
#define TW 64
#define TH 32
#define SCOLS 72          // staged cols: gx = tx0-4+lx (f4-aligned)
#define HROWS 38          // halo rows:  gy = ty0-3+hy
#define S1 22             // stage-1 rows 0..21 (covers px rows 0..15)
#define S2 (HROWS - S1)   // 16
#define KPR 18            // float4 chunks per halo row (72/4)
#define PITCH 44
#define NT 512
#define LDSZ (SCOLS * PITCH)   // 3168 dwords; max index 71*44+4+37 = 3165

__device__ __forceinline__ int refl(int v, int n) {
    return v < 0 ? -v : (v >= n ? 2 * n - 2 - v : v);
}
__device__ __forceinline__ int cbase(int lx) {      // swizzled column base
    return lx * PITCH + (((lx >> 2) & 7) << 2);     // stays 0 mod 4 -> 16B cols
}

// Load 10 consecutive column floats (16B-aligned) into registers.
__device__ __forceinline__ void load_col10(const float* col, float (&w)[10]) {
    const float4 a = *(const float4*)(col);
    const float4 b = *(const float4*)(col + 4);
    const float2 d = *(const float2*)(col + 8);
    w[0] = a.x; w[1] = a.y; w[2] = a.z; w[3] = a.w;
    w[4] = b.x; w[5] = b.y; w[6] = b.z; w[7] = b.w;
    w[8] = d.x; w[9] = d.y;
}

__global__ __launch_bounds__(NT, 8)
void census_fused(const float* __restrict__ pred,
                  const float* __restrict__ target,
                  float* __restrict__ out) {
    __shared__ __align__(16) float sP[LDSZ];
    __shared__ __align__(16) float sT[LDSZ];

    const int b   = blockIdx.z;
    const int ty0 = blockIdx.y * TH;
    const int tx0 = blockIdx.x * TW;
    const float* __restrict__ pb = pred   + (size_t)b * 3 * PLANE;
    const float* __restrict__ tb = target + (size_t)b * 3 * PLANE;
    const bool fastx = (blockIdx.x >= 1 && blockIdx.x <= 6);

    auto stage_fast = [&](int hy, int k) {          // one float4 chunk
        const int gy  = refl(ty0 + hy - 3, HH);
        const int off = gy * WW + tx0 - 4 + 4 * k;  // 16B-aligned
        const float4 pr = *(const float4*)(pb + off);
        const float4 pg = *(const float4*)(pb + off + PLANE);
        const float4 pc = *(const float4*)(pb + off + 2 * PLANE);
        const float4 tr = *(const float4*)(tb + off);
        const float4 tg = *(const float4*)(tb + off + PLANE);
        const float4 tc = *(const float4*)(tb + off + 2 * PLANE);
        const int lx = 4 * k;
        sP[cbase(lx + 0) + hy] = 0.299f * pr.x + 0.587f * pg.x + 0.114f * pc.x;
        sP[cbase(lx + 1) + hy] = 0.299f * pr.y + 0.587f * pg.y + 0.114f * pc.y;
        sP[cbase(lx + 2) + hy] = 0.299f * pr.z + 0.587f * pg.z + 0.114f * pc.z;
        sP[cbase(lx + 3) + hy] = 0.299f * pr.w + 0.587f * pg.w + 0.114f * pc.w;
        sT[cbase(lx + 0) + hy] = 0.299f * tr.x + 0.587f * tg.x + 0.114f * tc.x;
        sT[cbase(lx + 1) + hy] = 0.299f * tr.y + 0.587f * tg.y + 0.114f * tc.y;
        sT[cbase(lx + 2) + hy] = 0.299f * tr.z + 0.587f * tg.z + 0.114f * tc.z;
        sT[cbase(lx + 3) + hy] = 0.299f * tr.w + 0.587f * tg.w + 0.114f * tc.w;
    };
    auto stage_scalar = [&](int hy, int lx) {
        const int gy  = refl(ty0 + hy - 3, HH);
        const int gx  = refl(tx0 + lx - 4, WW);
        const int off = gy * WW + gx;
        sP[cbase(lx) + hy] = 0.299f * pb[off] + 0.587f * pb[off + PLANE] + 0.114f * pb[off + 2 * PLANE];
        sT[cbase(lx) + hy] = 0.299f * tb[off] + 0.587f * tb[off + PLANE] + 0.114f * tb[off + 2 * PLANE];
    };

    // ---- stage 1: halo rows 0..S1-1 (all 512 threads) ----
    if (fastx) {
        for (int idx = threadIdx.x; idx < S1 * KPR; idx += NT) {
            const int hy = idx / KPR;
            stage_fast(hy, idx - hy * KPR);
        }
    } else {
        for (int idx = threadIdx.x; idx < S1 * SCOLS; idx += NT) {
            const int hy = idx / SCOLS;
            stage_scalar(hy, idx - hy * SCOLS);
        }
    }
    __syncthreads();

    const int wv = threadIdx.x >> 6;   // wave == 4-row band
    const int c  = threadIdx.x & 63;   // pixel column in tile

    // Pixel (tx0+c, ty0+pr0+p), p=0..3: center at col c+4, halo row pr0+3+p;
    // window cols lx = c+1..c+7, halo rows pr0..pr0+9 (pr0 % 4 == 0).
    auto band_count = [&](int pr0) -> int {
        float wP[10], wT[10], cP[4], cT[4];
        int cnt = 0;
        load_col10(&sP[cbase(c + 4) + pr0], wP);    // dx = 0 column (holds centers)
        load_col10(&sT[cbase(c + 4) + pr0], wT);
        #pragma unroll
        for (int p = 0; p < 4; ++p) { cP[p] = wP[3 + p]; cT[p] = wT[3 + p]; }
        #pragma unroll
        for (int p = 0; p < 4; ++p) {
            #pragma unroll
            for (int dy = -3; dy <= 3; ++dy) {
                if (dy == 0) continue;              // skip center
                cnt += ((cP[p] > wP[3 + p + dy]) != (cT[p] > wT[3 + p + dy])) ? 1 : 0;
            }
        }
        #pragma unroll
        for (int t = 0; t < 6; ++t) {
            const int lx = c + 1 + (t < 3 ? t : t + 1);   // dx = -3..3, dx != 0
            load_col10(&sP[cbase(lx) + pr0], wP);
            load_col10(&sT[cbase(lx) + pr0], wT);
            #pragma unroll
            for (int p = 0; p < 4; ++p) {
                #pragma unroll
                for (int dy = -3; dy <= 3; ++dy)
                    cnt += ((cP[p] > wP[3 + p + dy]) != (cT[p] > wT[3 + p + dy])) ? 1 : 0;
            }
        }
        return cnt;
    };

    int cnt = 0;
    if (wv < 4) {
        // px rows 0..15 need only halo rows 0..21 (stage 1): compute now,
        // overlapped with waves 4..7 staging rows 22..37.
        cnt = band_count(wv * 4);
    } else {
        const int t2 = threadIdx.x - 256;
        if (fastx) {
            for (int idx = t2; idx < S2 * KPR; idx += 256) {
                const int r = idx / KPR;
                stage_fast(S1 + r, idx - r * KPR);
            }
        } else {
            for (int idx = t2; idx < S2 * SCOLS; idx += 256) {
                const int r = idx / SCOLS;
                stage_scalar(S1 + r, idx - r * SCOLS);
            }
        }
    }
    __syncthreads();
    if (wv >= 4) cnt = band_count(wv * 4);          // px rows 16..31

    // Reduce: 64-lane shuffle, cross-wave LDS, one atomic per block.
    #pragma unroll
    for (int o = 32; o > 0; o >>= 1) cnt += __shfl_down(cnt, o, 64);
    __shared__ int wsum[8];
    if ((threadIdx.x & 63) == 0) wsum[wv] = cnt;
    __syncthreads();
    if (threadIdx.x == 0) {
        int tot = 0;
        #pragma unroll
        for (int w = 0; w < 8; ++w) tot += wsum[w];
        // N = 8 * 48 * 512 * 512 = 100663296
        atomicAdd(out, (float)tot * (1.0f / 100663296.0f));
    }
}

extern "C" void kernel_launch(void* const* d_in, const int* in_sizes, int n_in,
                              void* d_out, int out_size, void* d_ws, size_t ws_size,
                              hipStream_t stream) {
    const float* pred   = (const float*)d_in[0];
    const float* target = (const float*)d_in[1];
    float* out = (float*)d_out;

    hipMemsetAsync(out, 0, sizeof(float), stream);   // d_out poisoned 0xAA

    dim3 grid(WW / TW, HH / TH, BATCH);              // (8, 16, 8) = 1024 blocks
    census_fused<<<grid, NT, 0, stream>>>(pred, target, out);
}

// Round 8
// 98.761 us; speedup vs baseline: 1.2505x; 1.2505x over previous
//
#include <hip/hip_runtime.h>

// CensusLoss = mean |census(pred)-census(target)| = mismatch_count / (8*48*512*512).
// Fused kernel, 64x32 tile, 512 threads, 4 px rows per thread — R3's proven
// spill-free structure (stage -> one sync -> one band_count call site).
//
// Post-mortems R4-R6: every kernel with the wave-split pipeline (band_count
// inlined at two divergent call sites, staging between) spilled ~90-170B/thread
// to scratch (WRITE_SIZE 44-47MB) and regressed; R3 without it was ~29us.
// => wave-split is banned. This round = R3 + two cheap staging upgrades:
//  - interior-x blocks stage with float4 global loads (8 vs 31 load instrs);
//  - LDS write swizzle cbase(lx) = lx*44 + 4*((lx>>2)&7): f4-path writes
//    spread over 8+ banks (was 2), columns stay 16B-aligned -> b128 reads.

#define BATCH 8
#define HH 512
#define WW 512
#define PLANE (HH * WW)
#define TW 64
#define TH 32
#define SCOLS 72          // staged cols: gx = tx0-4+lx (f4-aligned)
#define HROWS 38          // halo rows:  gy = ty0-3+hy
#define KPR 18            // float4 chunks per halo row (72/4)
#define PITCH 44
#define NT 512
#define LDSZ (SCOLS * PITCH)   // 3168 dwords; max index 71*44+4+37 = 3165

__device__ __forceinline__ int refl(int v, int n) {
    return v < 0 ? -v : (v >= n ? 2 * n - 2 - v : v);
}
__device__ __forceinline__ int cbase(int lx) {      // swizzled column base
    return lx * PITCH + (((lx >> 2) & 7) << 2);     // stays 0 mod 4 -> 16B cols
}

// Load 10 consecutive column floats (16B-aligned) into registers.
__device__ __forceinline__ void load_col10(const float* col, float (&w)[10]) {
    const float4 a = *(const float4*)(col);
    const float4 b = *(const float4*)(col + 4);
    const float2 d = *(const float2*)(col + 8);
    w[0] = a.x; w[1] = a.y; w[2] = a.z; w[3] = a.w;
    w[4] = b.x; w[5] = b.y; w[6] = b.z; w[7] = b.w;
    w[8] = d.x; w[9] = d.y;
}

__global__ __launch_bounds__(NT, 8)
void census_fused(const float* __restrict__ pred,
                  const float* __restrict__ target,
                  float* __restrict__ out) {
    __shared__ __align__(16) float sP[LDSZ];
    __shared__ __align__(16) float sT[LDSZ];

    const int b   = blockIdx.z;
    const int ty0 = blockIdx.y * TH;
    const int tx0 = blockIdx.x * TW;
    const float* __restrict__ pb = pred   + (size_t)b * 3 * PLANE;
    const float* __restrict__ tb = target + (size_t)b * 3 * PLANE;
    const bool fastx = (blockIdx.x >= 1 && blockIdx.x <= 6);  // gx always in range

    // ---- stage full 72x38 halo, then one barrier (R3 flow) ----
    if (fastx) {
        for (int idx = threadIdx.x; idx < HROWS * KPR; idx += NT) {
            const int hy = idx / KPR;
            const int k  = idx - hy * KPR;
            const int gy  = refl(ty0 + hy - 3, HH);
            const int off = gy * WW + tx0 - 4 + 4 * k;        // 16B-aligned
            const float4 pr = *(const float4*)(pb + off);
            const float4 pg = *(const float4*)(pb + off + PLANE);
            const float4 pc = *(const float4*)(pb + off + 2 * PLANE);
            const float4 tr = *(const float4*)(tb + off);
            const float4 tg = *(const float4*)(tb + off + PLANE);
            const float4 tc = *(const float4*)(tb + off + 2 * PLANE);
            const int lx = 4 * k;
            sP[cbase(lx + 0) + hy] = 0.299f * pr.x + 0.587f * pg.x + 0.114f * pc.x;
            sP[cbase(lx + 1) + hy] = 0.299f * pr.y + 0.587f * pg.y + 0.114f * pc.y;
            sP[cbase(lx + 2) + hy] = 0.299f * pr.z + 0.587f * pg.z + 0.114f * pc.z;
            sP[cbase(lx + 3) + hy] = 0.299f * pr.w + 0.587f * pg.w + 0.114f * pc.w;
            sT[cbase(lx + 0) + hy] = 0.299f * tr.x + 0.587f * tg.x + 0.114f * tc.x;
            sT[cbase(lx + 1) + hy] = 0.299f * tr.y + 0.587f * tg.y + 0.114f * tc.y;
            sT[cbase(lx + 2) + hy] = 0.299f * tr.z + 0.587f * tg.z + 0.114f * tc.z;
            sT[cbase(lx + 3) + hy] = 0.299f * tr.w + 0.587f * tg.w + 0.114f * tc.w;
        }
    } else {
        for (int idx = threadIdx.x; idx < HROWS * SCOLS; idx += NT) {
            const int hy = idx / SCOLS;
            const int lx = idx - hy * SCOLS;
            const int gy  = refl(ty0 + hy - 3, HH);
            const int gx  = refl(tx0 + lx - 4, WW);
            const int off = gy * WW + gx;
            sP[cbase(lx) + hy] = 0.299f * pb[off] + 0.587f * pb[off + PLANE] + 0.114f * pb[off + 2 * PLANE];
            sT[cbase(lx) + hy] = 0.299f * tb[off] + 0.587f * tb[off + PLANE] + 0.114f * tb[off + 2 * PLANE];
        }
    }
    __syncthreads();

    const int wv  = threadIdx.x >> 6;   // wave == 4-row band
    const int c   = threadIdx.x & 63;   // pixel column in tile
    const int pr0 = wv * 4;             // first pixel row (0,4,..,28); pr0 % 4 == 0

    // Pixel (tx0+c, ty0+pr0+p), p=0..3: center at col c+4, halo row pr0+3+p;
    // window cols lx = c+1..c+7, halo rows pr0..pr0+9. Single call site.
    float wP[10], wT[10], cP[4], cT[4];
    int cnt = 0;
    load_col10(&sP[cbase(c + 4) + pr0], wP);        // dx = 0 column (holds centers)
    load_col10(&sT[cbase(c + 4) + pr0], wT);
    #pragma unroll
    for (int p = 0; p < 4; ++p) { cP[p] = wP[3 + p]; cT[p] = wT[3 + p]; }
    #pragma unroll
    for (int p = 0; p < 4; ++p) {
        #pragma unroll
        for (int dy = -3; dy <= 3; ++dy) {
            if (dy == 0) continue;                  // skip center
            cnt += ((cP[p] > wP[3 + p + dy]) != (cT[p] > wT[3 + p + dy])) ? 1 : 0;
        }
    }
    #pragma unroll
    for (int t = 0; t < 6; ++t) {
        const int lx = c + 1 + (t < 3 ? t : t + 1); // dx = -3..3, dx != 0
        load_col10(&sP[cbase(lx) + pr0], wP);
        load_col10(&sT[cbase(lx) + pr0], wT);
        #pragma unroll
        for (int p = 0; p < 4; ++p) {
            #pragma unroll
            for (int dy = -3; dy <= 3; ++dy)
                cnt += ((cP[p] > wP[3 + p + dy]) != (cT[p] > wT[3 + p + dy])) ? 1 : 0;
        }
    }

    // Reduce: 64-lane shuffle, cross-wave LDS, one atomic per block.
    #pragma unroll
    for (int o = 32; o > 0; o >>= 1) cnt += __shfl_down(cnt, o, 64);
    __shared__ int wsum[8];
    if ((threadIdx.x & 63) == 0) wsum[wv] = cnt;
    __syncthreads();
    if (threadIdx.x == 0) {
        int tot = 0;
        #pragma unroll
        for (int w = 0; w < 8; ++w) tot += wsum[w];
        // N = 8 * 48 * 512 * 512 = 100663296
        atomicAdd(out, (float)tot * (1.0f / 100663296.0f));
    }
}

extern "C" void kernel_launch(void* const* d_in, const int* in_sizes, int n_in,
                              void* d_out, int out_size, void* d_ws, size_t ws_size,
                              hipStream_t stream) {
    const float* pred   = (const float*)d_in[0];
    const float* target = (const float*)d_in[1];
    float* out = (float*)d_out;

    hipMemsetAsync(out, 0, sizeof(float), stream);   // d_out poisoned 0xAA

    dim3 grid(WW / TW, HH / TH, BATCH);              // (8, 16, 8) = 1024 blocks
    census_fused<<<grid, NT, 0, stream>>>(pred, target, out);
}